// Round 12
// baseline (1287.482 us; speedup 1.0000x reference)
//
#include <hip/hip_runtime.h>
#include <hip/hip_cooperative_groups.h>

namespace cg = cooperative_groups;

#define H 0.1f

typedef float float4v __attribute__((ext_vector_type(4)));

__device__ __forceinline__ float bcast_lane(float v, int l) {
    return __int_as_float(__builtin_amdgcn_readlane(__float_as_int(v), l));
}

// ---- prep1: table (Wk,Wv) ∥ bounds (ptr) ∥ rootflag (mask) -----------------
__global__ void __launch_bounds__(256) prep1_kernel(
    const float* __restrict__ key_emb, const float* __restrict__ val_emb,
    const float* __restrict__ lw, const float* __restrict__ lb,
    float* __restrict__ Wk, float* __restrict__ Wv, int K,
    const int* __restrict__ erow, int* __restrict__ ptr, int n, int E,
    const int* __restrict__ roots, int* __restrict__ mask, int R,
    int TBLK, int BBLK)
{
    const int bid = blockIdx.x;
    if (bid < TBLK) {
        const int wv = bid * 4 + ((int)threadIdx.x >> 6);
        const int lane = threadIdx.x & 63;
        if (wv < 2 * K) {
            const int which = wv >= K;
            const int k = which ? wv - K : wv;
            float4v wreg[16];
            const float* wp = lw + (size_t)lane * 64;
#pragma unroll
            for (int q = 0; q < 16; ++q) wreg[q] = *(const float4v*)(wp + 4 * q);
            const float* emb = which ? val_emb : key_emb;
            float ev = emb[k * 64 + lane];
            float acc = which ? 0.f : lb[lane];
#pragma unroll
            for (int q = 0; q < 16; ++q)
#pragma unroll
                for (int j = 0; j < 4; ++j)
                    acc = fmaf(bcast_lane(ev, 4 * q + j), wreg[q][j], acc);
            (which ? Wv : Wk)[k * 64 + lane] = acc;
        }
    } else if (bid < TBLK + BBLK) {
        int e = (bid - TBLK) * 256 + threadIdx.x;
        if (e < E) {
            int b = erow[e];
            int a = (e == 0) ? -1 : erow[e - 1];
            for (int v = a + 1; v <= b; ++v) ptr[v] = e;
            if (e == E - 1)
                for (int v = b + 1; v <= n; ++v) ptr[v] = E;
        }
    } else {
        int i = (bid - TBLK - BBLK) * 256 + threadIdx.x;
        if (i < R) mask[roots[i]] = 1;
    }
}

// ---- prep2: init2 (X0) ∥ mark neighbors-of-roots (mask2) -------------------
__global__ void __launch_bounds__(256) prep2_kernel(
    const int* __restrict__ xnode, const float* __restrict__ Wk,
    const float* __restrict__ Wv, float* __restrict__ X0, int n,
    const int* __restrict__ erow, const int* __restrict__ ecol,
    const int* __restrict__ mask, int* __restrict__ mask2, int E, int IBLK)
{
    const int bid = blockIdx.x;
    if (bid < IBLK) {
        const int lane = threadIdx.x & 63;
        const int v = (bid * 256 + (int)threadIdx.x) >> 6;
        if (v < n) {
            unsigned k0 = (unsigned)__builtin_amdgcn_readfirstlane(xnode[2 * v + 0]);
            unsigned k1 = (unsigned)__builtin_amdgcn_readfirstlane(xnode[2 * v + 1]);
            float p = Wk[(k0 << 6) + lane] + Wv[(k1 << 6) + lane];
            X0[((unsigned)v << 6) + lane] = p > 0.f ? p : 0.f;
        }
    } else {
        int e = (bid - IBLK) * 256 + threadIdx.x;
        if (e < E && mask[erow[e]]) mask2[ecol[e]] = 1;
    }
}

// ---- scalar gather body (R6's best-measured form) --------------------------
__device__ __forceinline__ float wave_update(
    const float* __restrict__ Xin, float x, float xm1, int lane, int b, int e,
    const int* __restrict__ csr)
{
    const float* Xl = Xin + lane;
    float s0 = 0.f, s1 = 0.f, s2 = 0.f, s3 = 0.f;
    float s4 = 0.f, s5 = 0.f, s6 = 0.f, s7 = 0.f;
    int k = b;
    for (; k + 8 <= e; k += 8) {
        unsigned n0 = (unsigned)csr[k + 0], n1 = (unsigned)csr[k + 1];
        unsigned n2 = (unsigned)csr[k + 2], n3 = (unsigned)csr[k + 3];
        unsigned n4 = (unsigned)csr[k + 4], n5 = (unsigned)csr[k + 5];
        unsigned n6 = (unsigned)csr[k + 6], n7 = (unsigned)csr[k + 7];
        s0 += Xl[n0 << 6];
        s1 += Xl[n1 << 6];
        s2 += Xl[n2 << 6];
        s3 += Xl[n3 << 6];
        s4 += Xl[n4 << 6];
        s5 += Xl[n5 << 6];
        s6 += Xl[n6 << 6];
        s7 += Xl[n7 << 6];
    }
    if (k + 4 <= e) {
        unsigned n0 = (unsigned)csr[k + 0], n1 = (unsigned)csr[k + 1];
        unsigned n2 = (unsigned)csr[k + 2], n3 = (unsigned)csr[k + 3];
        s0 += Xl[n0 << 6];
        s1 += Xl[n1 << 6];
        s2 += Xl[n2 << 6];
        s3 += Xl[n3 << 6];
        k += 4;
    }
    for (; k < e; ++k) s0 += Xl[(unsigned)csr[k] << 6];
    float s = ((s0 + s1) + (s2 + s3)) + ((s4 + s5) + (s6 + s7));
    float lap = fmaf((float)(e - b), x, -s);
    return fmaf(-(H * H), lap, (x + x) - xm1);
}

// ---- one full wave step over all nodes (grid-stride, named restrict args) --
__device__ __forceinline__ void step_full(
    const float* __restrict__ Xin, const float* __restrict__ Xm1,
    float* __restrict__ Xout, const int* __restrict__ ptr,
    const int* __restrict__ csr, int n, int gwid, int NW, int lane)
{
    for (int v = gwid; v < n; v += NW) {
        const unsigned base = ((unsigned)v << 6) + lane;
        int b = __builtin_amdgcn_readfirstlane(ptr[v]);
        int e = __builtin_amdgcn_readfirstlane(ptr[v + 1]);
        float x = Xin[base];
        float xm1 = __builtin_nontemporal_load(&Xm1[base]);
        Xout[base] = wave_update(Xin, x, xm1, lane, b, e, csr);
    }
}

// ---- cooperative: all 7 wave steps, fully unrolled, 8 distinct planes ------
// R7 lesson: planes MUST be separate __restrict__ args. R11 lesson: the coop
// grid MUST come from the runtime occupancy query, or the launch silently
// fails (grid > co-resident capacity => hipErrorCooperativeLaunchTooLarge).
// launch_bounds(256,4): VGPR cap 128 (body measured 44), >=4 blk/CU.
__global__ void __launch_bounds__(256, 4) wave_all_kernel(
    float* __restrict__ p0, float* __restrict__ p1, float* __restrict__ p2,
    float* __restrict__ p3, float* __restrict__ p4, float* __restrict__ p5,
    float* __restrict__ p6, float* __restrict__ p7,
    const int* __restrict__ ptr, const int* __restrict__ csr,
    const int* __restrict__ mask, const int* __restrict__ mask2, int n)
{
    cg::grid_group grid = cg::this_grid();
    const int lane = threadIdx.x & 63;
    const int gwid = (int)((blockIdx.x * blockDim.x + threadIdx.x) >> 6);
    const int NW = (int)((gridDim.x * blockDim.x) >> 6);

    step_full(p0, p0, p1, ptr, csr, n, gwid, NW, lane);   // step 1 (xm1 = X0)
    grid.sync();
    step_full(p1, p0, p2, ptr, csr, n, gwid, NW, lane);   // step 2
    grid.sync();
    step_full(p2, p1, p3, ptr, csr, n, gwid, NW, lane);   // step 3
    grid.sync();
    step_full(p3, p2, p4, ptr, csr, n, gwid, NW, lane);   // step 4
    grid.sync();
    step_full(p4, p3, p5, ptr, csr, n, gwid, NW, lane);   // step 5
    grid.sync();
    step_full(p5, p4, p6, ptr, csr, n, gwid, NW, lane);   // step 6
    grid.sync();
    // step 7: cone-restricted (plane 7 read only at roots ∪ nbr(roots))
    for (int v = gwid; v < n; v += NW) {
        if (!(__builtin_amdgcn_readfirstlane(mask[v]) |
              __builtin_amdgcn_readfirstlane(mask2[v]))) continue;
        const unsigned base = ((unsigned)v << 6) + lane;
        int b = __builtin_amdgcn_readfirstlane(ptr[v]);
        int e = __builtin_amdgcn_readfirstlane(ptr[v + 1]);
        float x = p6[base];
        float xm1 = p5[base];
        p7[base] = wave_update(p6, x, xm1, lane, b, e, csr);
    }
}

// ---- per-step fallback (identical math), used if coop grid is tiny ---------
template <bool MASKED>
__global__ void __launch_bounds__(256) wave_step(
    const float* __restrict__ Xin, const float* __restrict__ Xm1,
    float* __restrict__ Xout, const int* __restrict__ ptr,
    const int* __restrict__ csr, int n,
    const int* __restrict__ mask, const int* __restrict__ mask2)
{
    const int lane = threadIdx.x & 63;
    const int v = (int)((blockIdx.x * blockDim.x + threadIdx.x) >> 6);
    if (v >= n) return;
    if (MASKED) {
        if (!(__builtin_amdgcn_readfirstlane(mask[v]) |
              __builtin_amdgcn_readfirstlane(mask2[v]))) return;
    }
    const unsigned base = ((unsigned)v << 6) + lane;
    int b = __builtin_amdgcn_readfirstlane(ptr[v]);
    int e = __builtin_amdgcn_readfirstlane(ptr[v + 1]);
    float x = Xin[base];
    float xm1 = __builtin_nontemporal_load(&Xm1[base]);
    Xout[base] = wave_update(Xin, x, xm1, lane, b, e, csr);
}

// ---- root_osc + inlined step-8 + final projection --------------------------
__global__ void __launch_bounds__(64) root_osc_final(
    const float* __restrict__ Xall, const int* __restrict__ roots,
    const float* __restrict__ osc_a, const float* __restrict__ Bw,
    const float* __restrict__ Bb, const float* __restrict__ fw,
    const int* __restrict__ ptr, const int* __restrict__ csr,
    float* __restrict__ out, int n, int R, int nout, size_t nd)
{
    const int lane = threadIdx.x;
    const int r = blockIdx.x;
    if (r >= R) return;
    const int v = __builtin_amdgcn_readfirstlane(roots[r]);

    const float* P7 = Xall + 7 * nd;
    const float* P6 = Xall + 6 * nd;
    const unsigned base = ((unsigned)v << 6) + lane;
    int b = __builtin_amdgcn_readfirstlane(ptr[v]);
    int e = __builtin_amdgcn_readfirstlane(ptr[v + 1]);
    float x8 = wave_update(P7, P7[base], P6[base], lane, b, e, csr);

    float hin[9], hout[9];

    {   // pass 0: layer 0, zprev = X^s (same step)
        float4v wreg[16];
        const float* wp = Bw + (size_t)lane * 64;
#pragma unroll
        for (int q = 0; q < 16; ++q) wreg[q] = *(const float4v*)(wp + 4 * q);
        const float aj = osc_a[lane];
        const float bj = Bb[lane];
        float z = 0.f, u = 0.f;
#pragma unroll
        for (int s = 1; s <= 8; ++s) {
            float zp = (s < 8) ? Xall[(size_t)s * nd + base] : x8;
            float acc = fmaf(aj, z, bj);
#pragma unroll
            for (int q = 0; q < 16; ++q)
#pragma unroll
                for (int j = 0; j < 4; ++j)
                    acc = fmaf(bcast_lane(zp, 4 * q + j), wreg[q][j], acc);
            float t = acc > 0.f ? acc : 0.f;
            u += H * t;
            z += H * u;
            hout[s] = z;
        }
    }

    auto pass = [&](int j, int prev_step) {
        float4v wreg[16];
        const float* wp = Bw + (size_t)j * 4096 + (size_t)lane * 64;
#pragma unroll
        for (int q = 0; q < 16; ++q) wreg[q] = *(const float4v*)(wp + 4 * q);
        const float aj = osc_a[j * 64 + lane];
        const float bj = Bb[j * 64 + lane];
        float z = 0.f, u = 0.f;
#pragma unroll
        for (int s = 1; s <= 8; ++s) {
            float zp = prev_step ? hin[s - 1] : hin[s];
            float acc = fmaf(aj, z, bj);
#pragma unroll
            for (int q = 0; q < 16; ++q)
#pragma unroll
                for (int jj = 0; jj < 4; ++jj)
                    acc = fmaf(bcast_lane(zp, 4 * q + jj), wreg[q][jj], acc);
            float t = acc > 0.f ? acc : 0.f;
            u += H * t;
            z += H * u;
            hout[s] = z;
        }
    };

    hin[0] = 0.f;
#pragma unroll
    for (int i = 1; i <= 8; ++i) hin[i] = hout[i];
    pass(1, 0);                     // layer1: zprev = z0^s (same step)
    hin[0] = 0.f;
#pragma unroll
    for (int i = 1; i <= 8; ++i) hin[i] = hout[i];
    pass(2, 1);                     // layer2: zprev = z1^{s-1}
    hin[0] = 0.f;
#pragma unroll
    for (int i = 1; i <= 8; ++i) hin[i] = hout[i];
    pass(3, 1);                     // layer3: zprev = z2^{s-1}

    float z3 = hout[8];
    for (int o = 0; o < nout; ++o) {
        float p = z3 * fw[o * 64 + lane];
#pragma unroll
        for (int off = 32; off > 0; off >>= 1)
            p += __shfl_xor(p, off);
        if (lane == 0) out[r * nout + o] = p;
    }
}

extern "C" void kernel_launch(void* const* d_in, const int* in_sizes, int n_in,
                              void* d_out, int out_size, void* d_ws, size_t ws_size,
                              hipStream_t stream)
{
    const int*   xnode   = (const int*)d_in[0];
    const int*   edge    = (const int*)d_in[1];
    const int*   roots   = (const int*)d_in[2];
    const float* key_emb = (const float*)d_in[3];
    const float* val_emb = (const float*)d_in[4];
    const float* lw      = (const float*)d_in[5];
    const float* lb      = (const float*)d_in[6];
    const float* osc_a   = (const float*)d_in[7];
    const float* Bw      = (const float*)d_in[8];
    const float* Bb      = (const float*)d_in[9];
    const float* fw      = (const float*)d_in[10];

    const int n = in_sizes[0] / 2;
    const int E = in_sizes[1] / 2;
    const int R = in_sizes[2];
    const int K = in_sizes[3] / 64;
    const int nout = out_size / R;
    const int* erow = edge;           // sorted ascending (np.unique axis=1)
    const int* ecol = edge + E;       // adjacency array of the row-CSR, in place

    const size_t nd = (size_t)n * 64;
    float* Xall  = (float*)d_ws;                     // 8*nd (planes 0..7)
    float* Wk    = Xall + 8 * nd;                    // K*64
    float* Wv    = Wk + (size_t)K * 64;              // K*64
    int*   ptr   = (int*)(Wv + (size_t)K * 64);      // n+1
    int*   mask  = ptr + n + 1;                      // n
    int*   mask2 = mask + n;                         // n

    hipMemsetAsync(mask, 0, (size_t)(2 * n) * sizeof(int), stream);

    const int TBLK = (2 * K + 3) / 4;
    const int BBLK = (E + 255) / 256;
    const int RBLK = (R + 255) / 256;
    prep1_kernel<<<TBLK + BBLK + RBLK, 256, 0, stream>>>(
        key_emb, val_emb, lw, lb, Wk, Wv, K, erow, ptr, n, E,
        roots, mask, R, TBLK, BBLK);

    const int IBLK = (n * 64 + 255) / 256;
    const int MBLK = (E + 255) / 256;
    prep2_kernel<<<IBLK + MBLK, 256, 0, stream>>>(
        xnode, Wk, Wv, Xall, n, erow, ecol, mask, mask2, E, IBLK);

    // --- coop grid from the runtime's own occupancy answer (capture-safe,
    // deterministic host queries; no stream interaction) ---
    int maxB = 0;
    hipOccupancyMaxActiveBlocksPerMultiprocessor(
        &maxB, (const void*)wave_all_kernel, 256, 0);
    int dev = 0;
    hipGetDevice(&dev);
    hipDeviceProp_t prop;
    hipGetDeviceProperties(&prop, dev);
    long coop_grid = (long)maxB * (long)prop.multiProcessorCount;
    if (coop_grid > 2048) coop_grid = 2048;

    float* p0 = Xall + 0 * nd; float* p1 = Xall + 1 * nd;
    float* p2 = Xall + 2 * nd; float* p3 = Xall + 3 * nd;
    float* p4 = Xall + 4 * nd; float* p5 = Xall + 5 * nd;
    float* p6 = Xall + 6 * nd; float* p7 = Xall + 7 * nd;

    if (coop_grid >= 256) {
        int n_ = n;
        void* args[] = { &p0, &p1, &p2, &p3, &p4, &p5, &p6, &p7,
                         (void*)&ptr, (void*)&ecol, (void*)&mask,
                         (void*)&mask2, &n_ };
        hipLaunchCooperativeKernel((void*)wave_all_kernel,
                                   dim3((uint32_t)coop_grid), dim3(256),
                                   args, 0, stream);
    } else {
        // fallback: per-step launches (R10 structure, identical math)
        const int nblocks = (n + 3) / 4;
        const float* planes[8] = { p0, p1, p2, p3, p4, p5, p6, p7 };
        for (int s = 1; s <= 6; ++s) {
            const float* xin = planes[s - 1];
            const float* xm1 = (s == 1) ? xin : planes[s - 2];
            wave_step<false><<<nblocks, 256, 0, stream>>>(
                xin, xm1, (float*)planes[s], ptr, ecol, n, nullptr, nullptr);
        }
        wave_step<true><<<nblocks, 256, 0, stream>>>(
            p6, p5, p7, ptr, ecol, n, mask, mask2);
    }

    root_osc_final<<<R, 64, 0, stream>>>(
        Xall, roots, osc_a, Bw, Bb, fw, ptr, ecol,
        (float*)d_out, n, R, nout, nd);
}

// Round 13
// 237.956 us; speedup vs baseline: 5.4106x; 5.4106x over previous
//
#include <hip/hip_runtime.h>

#define H 0.1f

typedef float float4v __attribute__((ext_vector_type(4)));

__device__ __forceinline__ float bcast_lane(float v, int l) {
    return __int_as_float(__builtin_amdgcn_readlane(__float_as_int(v), l));
}

// ---- prep1: table (Wk,Wv) ∥ bounds (ptr) ∥ rootflag (mask) -----------------
__global__ void __launch_bounds__(256) prep1_kernel(
    const float* __restrict__ key_emb, const float* __restrict__ val_emb,
    const float* __restrict__ lw, const float* __restrict__ lb,
    float* __restrict__ Wk, float* __restrict__ Wv, int K,
    const int* __restrict__ erow, int* __restrict__ ptr, int n, int E,
    const int* __restrict__ roots, int* __restrict__ mask, int R,
    int TBLK, int BBLK)
{
    const int bid = blockIdx.x;
    if (bid < TBLK) {
        const int wv = bid * 4 + ((int)threadIdx.x >> 6);
        const int lane = threadIdx.x & 63;
        if (wv < 2 * K) {
            const int which = wv >= K;
            const int k = which ? wv - K : wv;
            float4v wreg[16];
            const float* wp = lw + (size_t)lane * 64;
#pragma unroll
            for (int q = 0; q < 16; ++q) wreg[q] = *(const float4v*)(wp + 4 * q);
            const float* emb = which ? val_emb : key_emb;
            float ev = emb[k * 64 + lane];
            float acc = which ? 0.f : lb[lane];
#pragma unroll
            for (int q = 0; q < 16; ++q)
#pragma unroll
                for (int j = 0; j < 4; ++j)
                    acc = fmaf(bcast_lane(ev, 4 * q + j), wreg[q][j], acc);
            (which ? Wv : Wk)[k * 64 + lane] = acc;
        }
    } else if (bid < TBLK + BBLK) {
        int e = (bid - TBLK) * 256 + threadIdx.x;
        if (e < E) {
            int b = erow[e];
            int a = (e == 0) ? -1 : erow[e - 1];
            for (int v = a + 1; v <= b; ++v) ptr[v] = e;
            if (e == E - 1)
                for (int v = b + 1; v <= n; ++v) ptr[v] = E;
        }
    } else {
        int i = (bid - TBLK - BBLK) * 256 + threadIdx.x;
        if (i < R) mask[roots[i]] = 1;
    }
}

// ---- prep2: init2 (X0) ∥ mark neighbors-of-roots (mask2) -------------------
__global__ void __launch_bounds__(256) prep2_kernel(
    const int* __restrict__ xnode, const float* __restrict__ Wk,
    const float* __restrict__ Wv, float* __restrict__ X0, int n,
    const int* __restrict__ erow, const int* __restrict__ ecol,
    const int* __restrict__ mask, int* __restrict__ mask2, int E, int IBLK)
{
    const int bid = blockIdx.x;
    if (bid < IBLK) {
        const int lane = threadIdx.x & 63;
        const int v = (bid * 256 + (int)threadIdx.x) >> 6;
        if (v < n) {
            unsigned k0 = (unsigned)__builtin_amdgcn_readfirstlane(xnode[2 * v + 0]);
            unsigned k1 = (unsigned)__builtin_amdgcn_readfirstlane(xnode[2 * v + 1]);
            float p = Wk[(k0 << 6) + lane] + Wv[(k1 << 6) + lane];
            X0[((unsigned)v << 6) + lane] = p > 0.f ? p : 0.f;
        }
    } else {
        int e = (bid - IBLK) * 256 + threadIdx.x;
        if (e < E && mask[erow[e]]) mask2[ecol[e]] = 1;
    }
}

// ---- scalar gather body (best-measured form: 8-acc, 8-deep pipeline) -------
__device__ __forceinline__ float wave_update(
    const float* __restrict__ Xin, float x, float xm1, int lane, int b, int e,
    const int* __restrict__ csr)
{
    const float* Xl = Xin + lane;
    float s0 = 0.f, s1 = 0.f, s2 = 0.f, s3 = 0.f;
    float s4 = 0.f, s5 = 0.f, s6 = 0.f, s7 = 0.f;
    int k = b;
    for (; k + 8 <= e; k += 8) {
        unsigned n0 = (unsigned)csr[k + 0], n1 = (unsigned)csr[k + 1];
        unsigned n2 = (unsigned)csr[k + 2], n3 = (unsigned)csr[k + 3];
        unsigned n4 = (unsigned)csr[k + 4], n5 = (unsigned)csr[k + 5];
        unsigned n6 = (unsigned)csr[k + 6], n7 = (unsigned)csr[k + 7];
        s0 += Xl[n0 << 6];
        s1 += Xl[n1 << 6];
        s2 += Xl[n2 << 6];
        s3 += Xl[n3 << 6];
        s4 += Xl[n4 << 6];
        s5 += Xl[n5 << 6];
        s6 += Xl[n6 << 6];
        s7 += Xl[n7 << 6];
    }
    if (k + 4 <= e) {
        unsigned n0 = (unsigned)csr[k + 0], n1 = (unsigned)csr[k + 1];
        unsigned n2 = (unsigned)csr[k + 2], n3 = (unsigned)csr[k + 3];
        s0 += Xl[n0 << 6];
        s1 += Xl[n1 << 6];
        s2 += Xl[n2 << 6];
        s3 += Xl[n3 << 6];
        k += 4;
    }
    for (; k < e; ++k) s0 += Xl[(unsigned)csr[k] << 6];
    float s = ((s0 + s1) + (s2 + s3)) + ((s4 + s5) + (s6 + s7));
    float lap = fmaf((float)(e - b), x, -s);
    return fmaf(-(H * H), lap, (x + x) - xm1);
}

// ---- wave layer: 1 node per wave, 3-term leapfrog --------------------------
// NOTE (R7/R12 lesson): per-step launches with distinct __restrict__ args are
// REQUIRED — cooperative grid-fusion collapses this body to 20 VGPR
// (unpipelined gather, 6x slower) on this toolchain.
template <bool MASKED>
__global__ void __launch_bounds__(256) wave_step(
    const float* __restrict__ Xin, const float* __restrict__ Xm1,
    float* __restrict__ Xout, const int* __restrict__ ptr,
    const int* __restrict__ csr, int n,
    const int* __restrict__ mask, const int* __restrict__ mask2)
{
    const int lane = threadIdx.x & 63;
    const int v = (int)((blockIdx.x * blockDim.x + threadIdx.x) >> 6);
    if (v >= n) return;
    if (MASKED) {
        if (!(__builtin_amdgcn_readfirstlane(mask[v]) |
              __builtin_amdgcn_readfirstlane(mask2[v]))) return;
    }
    const unsigned base = ((unsigned)v << 6) + lane;
    int b = __builtin_amdgcn_readfirstlane(ptr[v]);
    int e = __builtin_amdgcn_readfirstlane(ptr[v + 1]);
    float x = Xin[base];
    float xm1 = __builtin_nontemporal_load(&Xm1[base]);   // last use of plane s-2
    Xout[base] = wave_update(Xin, x, xm1, lane, b, e, csr);
}

// ---- root_osc + inlined step-8 + final projection --------------------------
__global__ void __launch_bounds__(64) root_osc_final(
    const float* __restrict__ Xall, const int* __restrict__ roots,
    const float* __restrict__ osc_a, const float* __restrict__ Bw,
    const float* __restrict__ Bb, const float* __restrict__ fw,
    const int* __restrict__ ptr, const int* __restrict__ csr,
    float* __restrict__ out, int n, int R, int nout, size_t nd)
{
    const int lane = threadIdx.x;
    const int r = blockIdx.x;
    if (r >= R) return;
    const int v = __builtin_amdgcn_readfirstlane(roots[r]);

    // step 8 at the root only (X8 is never a gather source)
    const float* P7 = Xall + 7 * nd;
    const float* P6 = Xall + 6 * nd;
    const unsigned base = ((unsigned)v << 6) + lane;
    int b = __builtin_amdgcn_readfirstlane(ptr[v]);
    int e = __builtin_amdgcn_readfirstlane(ptr[v + 1]);
    float x8 = wave_update(P7, P7[base], P6[base], lane, b, e, csr);

    float hin[9], hout[9];

    {   // pass 0: layer 0, zprev = X^s (same step)
        float4v wreg[16];
        const float* wp = Bw + (size_t)lane * 64;
#pragma unroll
        for (int q = 0; q < 16; ++q) wreg[q] = *(const float4v*)(wp + 4 * q);
        const float aj = osc_a[lane];
        const float bj = Bb[lane];
        float z = 0.f, u = 0.f;
#pragma unroll
        for (int s = 1; s <= 8; ++s) {
            float zp = (s < 8) ? Xall[(size_t)s * nd + base] : x8;
            float acc = fmaf(aj, z, bj);
#pragma unroll
            for (int q = 0; q < 16; ++q)
#pragma unroll
                for (int j = 0; j < 4; ++j)
                    acc = fmaf(bcast_lane(zp, 4 * q + j), wreg[q][j], acc);
            float t = acc > 0.f ? acc : 0.f;
            u += H * t;
            z += H * u;
            hout[s] = z;
        }
    }

    auto pass = [&](int j, int prev_step) {
        float4v wreg[16];
        const float* wp = Bw + (size_t)j * 4096 + (size_t)lane * 64;
#pragma unroll
        for (int q = 0; q < 16; ++q) wreg[q] = *(const float4v*)(wp + 4 * q);
        const float aj = osc_a[j * 64 + lane];
        const float bj = Bb[j * 64 + lane];
        float z = 0.f, u = 0.f;
#pragma unroll
        for (int s = 1; s <= 8; ++s) {
            float zp = prev_step ? hin[s - 1] : hin[s];
            float acc = fmaf(aj, z, bj);
#pragma unroll
            for (int q = 0; q < 16; ++q)
#pragma unroll
                for (int jj = 0; jj < 4; ++jj)
                    acc = fmaf(bcast_lane(zp, 4 * q + jj), wreg[q][jj], acc);
            float t = acc > 0.f ? acc : 0.f;
            u += H * t;
            z += H * u;
            hout[s] = z;
        }
    };

    hin[0] = 0.f;
#pragma unroll
    for (int i = 1; i <= 8; ++i) hin[i] = hout[i];
    pass(1, 0);                     // layer1: zprev = z0^s (same step)
    hin[0] = 0.f;
#pragma unroll
    for (int i = 1; i <= 8; ++i) hin[i] = hout[i];
    pass(2, 1);                     // layer2: zprev = z1^{s-1}
    hin[0] = 0.f;
#pragma unroll
    for (int i = 1; i <= 8; ++i) hin[i] = hout[i];
    pass(3, 1);                     // layer3: zprev = z2^{s-1}

    float z3 = hout[8];
    for (int o = 0; o < nout; ++o) {
        float p = z3 * fw[o * 64 + lane];
#pragma unroll
        for (int off = 32; off > 0; off >>= 1)
            p += __shfl_xor(p, off);
        if (lane == 0) out[r * nout + o] = p;
    }
}

extern "C" void kernel_launch(void* const* d_in, const int* in_sizes, int n_in,
                              void* d_out, int out_size, void* d_ws, size_t ws_size,
                              hipStream_t stream)
{
    const int*   xnode   = (const int*)d_in[0];
    const int*   edge    = (const int*)d_in[1];
    const int*   roots   = (const int*)d_in[2];
    const float* key_emb = (const float*)d_in[3];
    const float* val_emb = (const float*)d_in[4];
    const float* lw      = (const float*)d_in[5];
    const float* lb      = (const float*)d_in[6];
    const float* osc_a   = (const float*)d_in[7];
    const float* Bw      = (const float*)d_in[8];
    const float* Bb      = (const float*)d_in[9];
    const float* fw      = (const float*)d_in[10];

    const int n = in_sizes[0] / 2;
    const int E = in_sizes[1] / 2;
    const int R = in_sizes[2];
    const int K = in_sizes[3] / 64;
    const int nout = out_size / R;
    const int* erow = edge;           // sorted ascending (np.unique axis=1)
    const int* ecol = edge + E;       // adjacency array of the row-CSR, in place

    const size_t nd = (size_t)n * 64;
    float* Xall  = (float*)d_ws;                     // 8*nd (planes 0..7)
    float* Wk    = Xall + 8 * nd;                    // K*64
    float* Wv    = Wk + (size_t)K * 64;              // K*64
    int*   ptr   = (int*)(Wv + (size_t)K * 64);      // n+1
    int*   mask  = ptr + n + 1;                      // n
    int*   mask2 = mask + n;                         // n

    hipMemsetAsync(mask, 0, (size_t)(2 * n) * sizeof(int), stream);

    const int TBLK = (2 * K + 3) / 4;
    const int BBLK = (E + 255) / 256;
    const int RBLK = (R + 255) / 256;
    prep1_kernel<<<TBLK + BBLK + RBLK, 256, 0, stream>>>(
        key_emb, val_emb, lw, lb, Wk, Wv, K, erow, ptr, n, E,
        roots, mask, R, TBLK, BBLK);

    const int IBLK = (n * 64 + 255) / 256;
    const int MBLK = (E + 255) / 256;
    prep2_kernel<<<IBLK + MBLK, 256, 0, stream>>>(
        xnode, Wk, Wv, Xall, n, erow, ecol, mask, mask2, E, IBLK);

    const int nblocks = (n + 3) / 4;  // 4 waves (1 node each) per block
    for (int s = 1; s <= 6; ++s) {    // step s: reads planes s-1, s-2; writes s
        const float* xin = Xall + (size_t)(s - 1) * nd;
        const float* xm1 = (s == 1) ? xin : Xall + (size_t)(s - 2) * nd;
        wave_step<false><<<nblocks, 256, 0, stream>>>(
            xin, xm1, Xall + (size_t)s * nd, ptr, ecol, n, nullptr, nullptr);
    }
    // step 7: reads planes 6,5; writes plane 7; cone-restricted
    wave_step<true><<<nblocks, 256, 0, stream>>>(
        Xall + 6 * nd, Xall + 5 * nd, Xall + 7 * nd, ptr, ecol, n, mask, mask2);

    root_osc_final<<<R, 64, 0, stream>>>(
        Xall, roots, osc_a, Bw, Bb, fw, ptr, ecol,
        (float*)d_out, n, R, nout, nd);
}